// Round 4
// baseline (748.668 us; speedup 1.0000x reference)
//
#include <hip/hip_runtime.h>
#include <hip/hip_bf16.h>

#define NTOK 4096
#define DM   1024
#define DF   4096
#define ROWS_TOTAL 12288   // 4096 shared + 8192 routed (top-2)
#define BM 128
#define BN 128
#define BK 64
#define SCALE_F 0.8944271909999159f
// worst-case sum of m-tiles over 9 experts: 32 (shared) + 71 (routed) = 103
#define PMAX 103

typedef __attribute__((ext_vector_type(8))) short short8;
typedef __attribute__((ext_vector_type(4))) float floatx4;

// async global->LDS, 16B/lane; LDS dest = wave-uniform base + lane*16 (m97/m104)
#define GLD16(gp, lp) __builtin_amdgcn_global_load_lds( \
    (const __attribute__((address_space(1))) void*)(gp), \
    (__attribute__((address_space(3))) void*)(lp), 16, 0, 0)

__device__ __forceinline__ ushort f2bf(float f){
    __hip_bfloat16 h = __float2bfloat16(f);
    return *reinterpret_cast<ushort*>(&h);
}

// 0.5x(1+tanh(u)) == x * sigmoid(2u), exp-form
__device__ __forceinline__ float gelu_tanh(float v){
    float u2 = -1.5957691216057308f * (v + 0.044715f * v * v * v);
    return v / (1.0f + __expf(u2));
}

// one wave per token: fp32 logits -> softmax -> top2; also emits bf16 x
__global__ __launch_bounds__(256) void router_kernel(
    const float* __restrict__ x, const float* __restrict__ wr,
    int* __restrict__ te, float* __restrict__ tg, int* __restrict__ tokarr,
    ushort* __restrict__ xb)
{
    const int token = blockIdx.x * 4 + (threadIdx.x >> 6);
    const int lane  = threadIdx.x & 63;
    const float* xp = x + (size_t)token * DM;
    float s[8];
    #pragma unroll
    for (int e = 0; e < 8; e++) s[e] = 0.f;
    for (int d = lane; d < DM; d += 64){
        float xv = xp[d];
        xb[(size_t)token * DM + d] = f2bf(xv);   // fused x->bf16 (coalesced)
        #pragma unroll
        for (int e = 0; e < 8; e++) s[e] += xv * wr[e * DM + d];
    }
    #pragma unroll
    for (int e = 0; e < 8; e++){
        float v = s[e];
        #pragma unroll
        for (int off = 32; off > 0; off >>= 1) v += __shfl_down(v, off);
        s[e] = v;
    }
    if (lane == 0){
        float m = s[0];
        #pragma unroll
        for (int e = 1; e < 8; e++) m = fmaxf(m, s[e]);
        float p[8]; float sum = 0.f;
        #pragma unroll
        for (int e = 0; e < 8; e++){ p[e] = __expf(s[e] - m); sum += p[e]; }
        float inv = 1.f / sum;
        #pragma unroll
        for (int e = 0; e < 8; e++) p[e] *= inv;
        int i1 = 0; float p1 = p[0];
        #pragma unroll
        for (int e = 1; e < 8; e++) if (p[e] > p1){ p1 = p[e]; i1 = e; }
        int i2 = -1; float p2 = -1.f;
        #pragma unroll
        for (int e = 0; e < 8; e++) if (e != i1 && p[e] > p2){ p2 = p[e]; i2 = e; }
        te[token*2+0] = i1; te[token*2+1] = i2;
        tg[token*2+0] = p1; tg[token*2+1] = p2;
        tokarr[token] = token;      // shared-expert rows = identity
    }
}

// single block, ballot-rank compaction (no same-address atomics).
// meta: [0..8]=counts, [16..24]=rowbase, [32..40]=mtiles
__global__ __launch_bounds__(256) void plan_kernel(
    const int* __restrict__ te, int* __restrict__ tokarr,
    int* __restrict__ rowof, int* __restrict__ meta)
{
    __shared__ int wcnt[4][32][8];
    __shared__ int ebase[8];
    const int t = threadIdx.x;
    const int w = t >> 6, l = t & 63;
    for (int r = 0; r < 32; r++){
        int e = te[w*2048 + r*64 + l];
        #pragma unroll
        for (int ee = 0; ee < 8; ee++){
            unsigned long long m = __ballot(e == ee);
            if (l == 0) wcnt[w][r][ee] = __popcll(m);
        }
    }
    __syncthreads();
    if (t < 8){
        int run = 0;
        for (int w2 = 0; w2 < 4; w2++)
            for (int r = 0; r < 32; r++){
                int v = wcnt[w2][r][t];
                wcnt[w2][r][t] = run;
                run += v;
            }
        ebase[t] = run;   // temporarily: total count
    }
    __syncthreads();
    if (t == 0){
        int off = NTOK;
        for (int e = 0; e < 8; e++){
            int c = ebase[e];
            meta[e]    = c;
            meta[16+e] = off;
            meta[32+e] = (c + BM - 1) / BM;
            ebase[e]   = off;
            off += c;
        }
        meta[8]    = NTOK;      // shared expert
        meta[16+8] = 0;
        meta[32+8] = NTOK / BM;
    }
    __syncthreads();
    for (int r = 0; r < 32; r++){
        int j = w*2048 + r*64 + l;
        int e = te[j];
        int rank = 0;
        #pragma unroll
        for (int ee = 0; ee < 8; ee++){
            unsigned long long m = __ballot(e == ee);
            if (e == ee) rank = __popcll(m & ((1ull << l) - 1ull));
        }
        int p = ebase[e] + wcnt[w][r][e] + rank;
        tokarr[p] = j >> 1;
        rowof[j]  = p;
    }
}

// MODE 0: H[row] = gelu(Xg @ W1_e^T + b1)   (N=4096, K=1024) -> bf16 H
// MODE 1: Y[row] = H @ W2_e^T + b2          (N=1024, K=4096) -> fp32 Y
// A staged bf16; B staged fp32 DIRECTLY from input weights (no cvt pass),
// converted to bf16 at fragment-read time. XCD-aware schedule as before.
template<int MODE>
__global__ __launch_bounds__(256) void gemm_kernel(
    const ushort* __restrict__ Abase,
    const float* __restrict__ Wb, const float* __restrict__ Wsb,
    const float* __restrict__ brout, const float* __restrict__ bsh,
    const int* __restrict__ meta, const int* __restrict__ tokarr,
    ushort* __restrict__ Hout, float* __restrict__ Yout)
{
    const int xcd = blockIdx.x & 7;
    const int q   = blockIdx.x >> 3;
    const int NTG = (MODE == 0) ? 4 : 1;

    int e = -1, r = 0, a0 = 0;
    #pragma unroll
    for (int ee = 0; ee < 9; ee++){
        int w = NTG * meta[32 + ee];
        if (e < 0 && q < a0 + w){ e = ee; r = q - a0; }
        a0 += w;
    }
    if (e < 0) return;
    const int mt_e = meta[32 + e];
    int ntg, mti;
    if (MODE == 0){ ntg = r / mt_e; mti = r - ntg * mt_e; }
    else          { ntg = 0;        mti = r; }
    const int nt   = (MODE == 0) ? (xcd + 8 * ntg) : xcd;
    const int cnt  = meta[e];
    const int base = meta[16 + e];

    const int K = (MODE == 0) ? DM : DF;
    const int N = (MODE == 0) ? DF : DM;
    const float* Bp   = (e < 8) ? (Wb + (size_t)e * DF * DM) : Wsb;
    const float* bias = (e < 8) ? (brout + e * N) : bsh;

    __shared__ ushort As[BM * BK];    // 16 KB bf16
    __shared__ float  Bsf[BN * BK];   // 32 KB fp32

    const int t    = threadIdx.x;
    const int lane = t & 63;
    const int wv   = t >> 6;
    const int wm   = (wv >> 1) * 64;
    const int wn   = (wv & 1) * 64;
    const int lrow = lane & 15;
    const int quad = lane >> 4;

    // ---- A staging (bf16): 4 GLD16, 8 rows each; seg=16B=8 bf16
    // LDS[r][phys] = G[r][phys ^ (r&7)]
    const ushort* Ap[4];
    ushort* Alds[4];
    const int aswz = ((lane & 7) ^ (lane >> 3)) * 8;
    #pragma unroll
    for (int i = 0; i < 4; i++){
        int rin = wv * 32 + i * 8 + (lane >> 3);
        int pos = mti * BM + rin;
        int clp = (pos < cnt) ? pos : (cnt - 1);
        if (MODE == 0) Ap[i] = Abase + (size_t)tokarr[base + clp] * DM + aswz;
        else           Ap[i] = Abase + (size_t)(base + clp) * DF + aswz;
        Alds[i] = &As[(wv * 32 + i * 8) * BK];
    }
    // ---- B staging (fp32): 8 GLD16, 4 rows each; seg=16B=4 fp32 (16 segs/row)
    const float* Bpp[8];
    float* Blds[8];
    #pragma unroll
    for (int i = 0; i < 8; i++){
        int rin = wv * 32 + i * 4 + (lane >> 4);
        int sgl = (lane & 15) ^ (rin & 7);           // logical 16B seg in k
        Bpp[i]  = Bp + (size_t)(nt * BN + rin) * K + sgl * 4;
        Blds[i] = &Bsf[(wv * 32 + i * 4) * BK];
    }

    floatx4 acc[4][4];
    #pragma unroll
    for (int mi = 0; mi < 4; mi++)
        #pragma unroll
        for (int ni = 0; ni < 4; ni++)
            acc[mi][ni] = (floatx4){0.f, 0.f, 0.f, 0.f};

    const float4* Bs4 = reinterpret_cast<const float4*>(Bsf);

    for (int k0 = 0; k0 < K; k0 += BK){
        __syncthreads();
        #pragma unroll
        for (int i = 0; i < 4; i++) GLD16(Ap[i] + k0, Alds[i]);
        #pragma unroll
        for (int i = 0; i < 8; i++) GLD16(Bpp[i] + k0, Blds[i]);
        __syncthreads();   // vmcnt(0) drain + barrier (m97 structure)
        #pragma unroll
        for (int kk = 0; kk < BK; kk += 32){
            short8 af[4], bfr[4];
            #pragma unroll
            for (int mi = 0; mi < 4; mi++){
                int row  = wm + mi * 16 + lrow;
                int phys = ((kk >> 3) + quad) ^ (row & 7);
                af[mi] = *reinterpret_cast<const short8*>(&As[row * BK + phys * 8]);
            }
            #pragma unroll
            for (int ni = 0; ni < 4; ni++){
                int row = wn + ni * 16 + lrow;
                int kw0 = (kk >> 2) + quad * 2;          // 16B seg of k[0..3]
                float4 d0 = Bs4[row * 16 + (kw0      ^ (row & 7))];
                float4 d1 = Bs4[row * 16 + ((kw0 + 1) ^ (row & 7))];
                short8 b;
                b[0] = (short)f2bf(d0.x); b[1] = (short)f2bf(d0.y);
                b[2] = (short)f2bf(d0.z); b[3] = (short)f2bf(d0.w);
                b[4] = (short)f2bf(d1.x); b[5] = (short)f2bf(d1.y);
                b[6] = (short)f2bf(d1.z); b[7] = (short)f2bf(d1.w);
                bfr[ni] = b;
            }
            #pragma unroll
            for (int mi = 0; mi < 4; mi++)
                #pragma unroll
                for (int ni = 0; ni < 4; ni++)
                    acc[mi][ni] = __builtin_amdgcn_mfma_f32_16x16x32_bf16(af[mi], bfr[ni], acc[mi][ni], 0, 0, 0);
        }
    }

    // epilogue; C/D: col = lane&15, row = quad*4 + reg  [m89]
    float bv[4];
    #pragma unroll
    for (int ni = 0; ni < 4; ni++) bv[ni] = bias[nt * BN + wn + ni*16 + lrow];

    #pragma unroll
    for (int mi = 0; mi < 4; mi++){
        #pragma unroll
        for (int rg = 0; rg < 4; rg++){
            int s   = wm + mi*16 + quad*4 + rg;
            int pos = mti * BM + s;
            if (pos >= cnt) continue;
            int rr = base + pos;
            if (MODE == 0){
                ushort* hp = Hout + (size_t)rr * DF + nt * BN;
                #pragma unroll
                for (int ni = 0; ni < 4; ni++){
                    float v = acc[mi][ni][rg] + bv[ni];
                    hp[wn + ni*16 + lrow] = f2bf(gelu_tanh(v));
                }
            } else {
                float* yp = Yout + (size_t)rr * DM + nt * BN;
                #pragma unroll
                for (int ni = 0; ni < 4; ni++)
                    yp[wn + ni*16 + lrow] = acc[mi][ni][rg] + bv[ni];
            }
        }
    }
}

// out[t] = SCALE * (Y[t] + g1*Y[r1] + g2*Y[r2])
__global__ __launch_bounds__(256) void combine_kernel(
    const float* __restrict__ Y, const int* __restrict__ rowof,
    const float* __restrict__ tg, float* __restrict__ out)
{
    const int token = blockIdx.x;
    const int d4    = threadIdx.x;
    const float4* Y4 = reinterpret_cast<const float4*>(Y);
    int r1 = rowof[token*2+0], r2 = rowof[token*2+1];
    float g1 = tg[token*2+0],  g2 = tg[token*2+1];
    float4 a = Y4[(size_t)token * 256 + d4];
    float4 b = Y4[(size_t)r1 * 256 + d4];
    float4 c = Y4[(size_t)r2 * 256 + d4];
    float4 o;
    o.x = SCALE_F * (a.x + g1*b.x + g2*c.x);
    o.y = SCALE_F * (a.y + g1*b.y + g2*c.y);
    o.z = SCALE_F * (a.z + g1*b.z + g2*c.z);
    o.w = SCALE_F * (a.w + g1*b.w + g2*c.w);
    reinterpret_cast<float4*>(out)[(size_t)token * 256 + d4] = o;
}

extern "C" void kernel_launch(void* const* d_in, const int* in_sizes, int n_in,
                              void* d_out, int out_size, void* d_ws, size_t ws_size,
                              hipStream_t stream) {
    const float* x   = (const float*)d_in[0];
    const float* wr  = (const float*)d_in[1];
    const float* W1  = (const float*)d_in[2];
    const float* b1  = (const float*)d_in[3];
    const float* W2  = (const float*)d_in[4];
    const float* b2  = (const float*)d_in[5];
    const float* Ws1 = (const float*)d_in[6];
    const float* bs1 = (const float*)d_in[7];
    const float* Ws2 = (const float*)d_in[8];
    const float* bs2 = (const float*)d_in[9];
    float* out = (float*)d_out;

    char* ws = (char*)d_ws;
    size_t off = 0;
    auto wsalloc = [&](size_t bytes) -> char* {
        char* p = ws + off;
        off += (bytes + 255) & ~(size_t)255;
        return p;
    };
    ushort* xb   = (ushort*)wsalloc((size_t)NTOK * DM * 2);          //   8.4 MB
    ushort* H    = (ushort*)wsalloc((size_t)ROWS_TOTAL * DF * 2);    // 100.7 MB
    float*  Y    = (float*) wsalloc((size_t)ROWS_TOTAL * DM * 4);    //  50.3 MB
    int*    tokarr = (int*)wsalloc(ROWS_TOTAL * 4);
    int*    rowof  = (int*)wsalloc(NTOK * 2 * 4);
    int*    te     = (int*)wsalloc(NTOK * 2 * 4);
    float*  tg     = (float*)wsalloc(NTOK * 2 * 4);
    int*    meta   = (int*)wsalloc(64 * 4);

    router_kernel<<<NTOK/4, 256, 0, stream>>>(x, wr, te, tg, tokarr, xb);
    plan_kernel<<<1, 256, 0, stream>>>(te, tokarr, rowof, meta);

    gemm_kernel<0><<<8 * 4 * PMAX, 256, 0, stream>>>(xb, W1, Ws1, b1, bs1,
        meta, tokarr, H, Y);
    gemm_kernel<1><<<8 * PMAX, 256, 0, stream>>>(H, W2, Ws2, b2, bs2,
        meta, tokarr, H, Y);

    combine_kernel<<<NTOK, 256, 0, stream>>>(Y, rowof, tg, out);
}